// Round 3
// baseline (622.509 us; speedup 1.0000x reference)
//
#include <hip/hip_runtime.h>

typedef unsigned short u16;
typedef unsigned int   u32;
typedef __bf16  bf16x8 __attribute__((ext_vector_type(8)));
typedef float   f32x4  __attribute__((ext_vector_type(4)));

__device__ __forceinline__ float bf2f(u16 u) {
    u32 v = ((u32)u) << 16;
    return __builtin_bit_cast(float, v);
}
__device__ __forceinline__ u16 f2bf(float f) {
    u32 u = __builtin_bit_cast(u32, f);
    return (u16)((u + 0x7FFFu + ((u >> 16) & 1u)) >> 16);   // RNE
}
__device__ __forceinline__ float ldf(const void* p, long i, int f32) {
    return f32 ? ((const float*)p)[i] : bf2f(((const u16*)p)[i]);
}
__device__ __forceinline__ int is_f32(const u32* im) {
    return im[0] == 0x43E00000u;   // 448.0f fp32 vs packed bf16 (0x43E043E0)
}
// async global->LDS, 16B per lane (LDS dst = wave-uniform base + lane*16)
__device__ __forceinline__ void gl2lds16(const u16* g, u16* l) {
    __builtin_amdgcn_global_load_lds(
        (const __attribute__((address_space(1))) void*)g,
        (__attribute__((address_space(3))) void*)l, 16, 0, 0);
}

// ---------------------------------------------------------------- zero (xpad)
__global__ void zero_kernel(uint4* __restrict__ p, const int n)
{
    int i = blockIdx.x * 256 + threadIdx.x;
    if (i < n) p[i] = uint4{0u, 0u, 0u, 0u};
}

// ------------------------------------------------- pad+transpose base_feat
__global__ void pad_fill(const void* __restrict__ src, u16* __restrict__ xpad,
                         const u32* __restrict__ im)
{
    const int f32 = is_f32(im);
    __shared__ u16 lds[56 * 40];
    int blk = blockIdx.x;
    const int h2  = blk % 14;  blk /= 14;
    const int c32 = blk & 15;  blk >>= 4;
    const int t   = blk & 15;
    const int b   = blk >> 4;
    const int tid = threadIdx.x;
    const long sbase = ((long)(b * 512 + c32 * 32) * 16 + t) * 784 + h2 * 56;
    #pragma unroll
    for (int it = tid; it < 1792; it += 256) {
        const int c = it / 56, p = it - c * 56;
        float v = f32 ? ((const float*)src)[sbase + (long)c * 12544 + p]
                      : bf2f(((const u16*)src)[sbase + (long)c * 12544 + p]);
        lds[p * 40 + c] = f2bf(v);
    }
    __syncthreads();
    if (tid < 224) {
        const int p = tid >> 2, g = tid & 3;
        const int h = h2 * 2 + p / 28, w = p % 28;
        const long o = (((long)(b * 18 + t + 1) * 30 + h + 1) * 30 + (w + 1)) * 512
                       + c32 * 32 + g * 8;
        *(uint4*)&xpad[o] = *(const uint4*)&lds[p * 40 + g * 8];
    }
}

// ------------------------------------------------- W_conv [O][I][27] -> Wt[27][O][I]
__global__ void wt_transform(const void* __restrict__ wconv, u16* __restrict__ wt,
                             const u32* __restrict__ im)
{
    const int f32 = is_f32(im);
    __shared__ u16 lds[256 * 28];
    const int tid = threadIdx.x;
    const int pair_base = blockIdx.x * 256;
    const long s0 = (long)pair_base * 27;
    for (int it = tid; it < 256 * 27; it += 256) {
        const int p = it / 27, o = it - p * 27;
        float v = f32 ? ((const float*)wconv)[s0 + it]
                      : bf2f(((const u16*)wconv)[s0 + it]);
        lds[p * 28 + o] = f2bf(v);
    }
    __syncthreads();
    #pragma unroll
    for (int off = 0; off < 27; ++off)
        wt[(long)off * 262144 + pair_base + tid] = lds[tid * 28 + off];
}

// ------------------------------------------------- head weights + biases (merged)
__global__ void cvt_all(const void* s0, const void* s1, const void* s2,
                        const void* s3, const void* s4,
                        const void* b0, const void* b1, const void* b2,
                        const void* b3, const void* b4, const void* b5,
                        u16* __restrict__ whd, float* __restrict__ bfs,
                        const u32* __restrict__ im)
{
    const int f32 = is_f32(im);
    int i = blockIdx.x * 256 + threadIdx.x;
    if (i < 1244160) {
        const void* s; long j;
        if      (i < 15360)   { s = s0; j = i; }
        else if (i < 506880)  { s = s1; j = i - 15360; }
        else if (i < 875520)  { s = s2; j = i - 506880; }
        else if (i < 1121280) { s = s3; j = i - 875520; }
        else                  { s = s4; j = i - 1121280; }
        whd[i] = f2bf(ldf(s, j, f32));
        return;
    }
    i -= 1244160;
    if (i >= 2942) return;
    float v;
    if      (i < 512)  v = ldf(b0, i, f32);
    else if (i < 542)  v = ldf(b1, i - 512, f32);
    else if (i < 1502) v = ldf(b2, i - 542, f32);
    else if (i < 2222) v = ldf(b3, i - 1502, f32);
    else if (i < 2702) v = ldf(b4, i - 2222, f32);
    else               v = ldf(b5, i - 2702, f32);
    bfs[i] = v;
}

// ---------------------------------------------------------------- conv GEMM (R6)
// 256x256 tile, BK=32, ring-4 LDS (128 KiB), SINGLE barrier per K-tile:
//   vmcnt(gate) ; s_barrier ; 12 ds_read_b128 ; 4 gl2lds stages ; 32 MFMA.
// vmcnt gate is per-wave but every wave gates its OWN loads before the shared
// barrier -> all loads for the tile-to-read complete before any wave reads.
__global__ __launch_bounds__(512, 2) void conv_gemm256(
    const u16* __restrict__ xpad, const u16* __restrict__ wt,
    const float* __restrict__ bfs, u16* __restrict__ y)
{
    __shared__ u16 smem[65536];           // 4 bufs x (A 8192 + B 8192) u16
    const int tid = threadIdx.x;

    // bijective XCD remap (m204, nwg=196), pair-major so (n,m0),(n,m1) co-XCD
    const int bx  = blockIdx.x;
    const int xcd = bx & 7, pos = bx >> 3;
    const int L   = (xcd < 4 ? xcd * 25 : 100 + (xcd - 4) * 24) + pos;
    const int m_base = (L & 1) * 256;
    const int n_base = (L >> 1) * 256;

    const int rq  = tid >> 2;                                  // 0..127
    const int gsw = (((tid & 3) ^ ((tid >> 3) & 3))) * 8;      // elems
    const u16* pa0 = wt + (long)(m_base + rq) * 512 + gsw;
    const u16* pa1 = pa0 + 128 * 512;

    const int n0 = n_base + rq;
    const int n1 = n0 + 128;
    int b0 = n0 / 12544, r0 = n0 % 12544;
    int t0 = r0 / 784,   q0 = r0 % 784;
    int h0 = q0 / 28,    w0 = q0 % 28;
    int b1 = n1 / 12544, r1 = n1 % 12544;
    int t1 = r1 / 784,   q1 = r1 % 784;
    int h1 = q1 / 28,    w1 = q1 % 28;
    const int sa0 = ((b0 * 18 + t0) * 30 + h0) * 30 + w0;
    const int sa1 = ((b1 * 18 + t1) * 30 + h1) * 30 + w1;
    const u16* pb0 = xpad + (long)sa0 * 512 + gsw;
    const u16* pb1 = xpad + (long)sa1 * 512 + gsw;

    const int lane = tid & 63, wid = tid >> 6;
    const int l16 = lane & 15, quad = lane >> 4;
    const int wm = wid >> 2;              // 0..1 -> 128 rows
    const int wn = wid & 3;               // 0..3 -> 64 cols
    const int slot  = (quad ^ ((l16 >> 1) & 3)) * 8;
    const int aoffs = (wm * 128 + l16) * 32 + slot;            // + mi*512
    const int boffs = 8192 + (wn * 64 + l16) * 32 + slot;      // + ni*512

    f32x4 acc[8][4] = {};

    // prologue: stage K-tiles 0..2 (12 gl2lds in flight)
    #pragma unroll
    for (int k = 0; k < 3; ++k) {
        u16* dst = smem + (k << 14);
        gl2lds16(pa0 + k * 32, dst + tid * 8);
        gl2lds16(pa1 + k * 32, dst + 4096  + tid * 8);
        gl2lds16(pb0 + k * 32, dst + 8192  + tid * 8);
        gl2lds16(pb1 + k * 32, dst + 12288 + tid * 8);
    }

#define KTILE(ktl, STG, GATE)                                                  \
    {                                                                          \
        asm volatile("s_waitcnt vmcnt(" #GATE ")" ::: "memory");               \
        asm volatile("s_barrier" ::: "memory");                                \
        const u16* buf = smem + (((ktl) & 3) << 14);                           \
        bf16x8 af[8], bfr[4];                                                  \
        _Pragma("unroll")                                                      \
        for (int mi = 0; mi < 4; ++mi)                                         \
            af[mi] = *(const bf16x8*)&buf[aoffs + mi * 512];                   \
        _Pragma("unroll")                                                      \
        for (int ni = 0; ni < 4; ++ni)                                         \
            bfr[ni] = *(const bf16x8*)&buf[boffs + ni * 512];                  \
        _Pragma("unroll")                                                      \
        for (int mi = 4; mi < 8; ++mi)                                         \
            af[mi] = *(const bf16x8*)&buf[aoffs + mi * 512];                   \
        if (STG) {                                                             \
            const int kts = (ktl) + 3;                                         \
            const int tap = kts >> 4, kc = kts & 15;                           \
            const int kd = tap / 9, r9 = tap - kd * 9;                         \
            const int kh = r9 / 3,  kw = r9 - kh * 3;                          \
            const long aoff = (long)tap * 262144 + kc * 32;                    \
            const long boff = (long)(kd * 900 + kh * 30 + kw) * 512 + kc * 32; \
            u16* dst = smem + ((kts & 3) << 14);                               \
            gl2lds16(pa0 + aoff, dst + tid * 8);                               \
            gl2lds16(pa1 + aoff, dst + 4096  + tid * 8);                       \
            gl2lds16(pb0 + boff, dst + 8192  + tid * 8);                       \
            gl2lds16(pb1 + boff, dst + 12288 + tid * 8);                       \
        }                                                                      \
        __builtin_amdgcn_s_setprio(1);                                         \
        _Pragma("unroll")                                                      \
        for (int mi = 0; mi < 4; ++mi)                                         \
            _Pragma("unroll")                                                  \
            for (int ni = 0; ni < 4; ++ni)                                     \
                acc[mi][ni] = __builtin_amdgcn_mfma_f32_16x16x32_bf16(         \
                    af[mi], bfr[ni], acc[mi][ni], 0, 0, 0);                    \
        _Pragma("unroll")                                                      \
        for (int mi = 4; mi < 8; ++mi)                                         \
            _Pragma("unroll")                                                  \
            for (int ni = 0; ni < 4; ++ni)                                     \
                acc[mi][ni] = __builtin_amdgcn_mfma_f32_16x16x32_bf16(         \
                    af[mi], bfr[ni], acc[mi][ni], 0, 0, 0);                    \
        __builtin_amdgcn_s_setprio(0);                                         \
    }

    for (int kt = 0; kt < 429; ++kt) KTILE(kt, 1, 8)
    KTILE(429, 0, 8)
    KTILE(430, 0, 4)
    KTILE(431, 0, 0)
#undef KTILE

    // epilogue: bias + relu + bf16 store to y[n][512]
    #pragma unroll
    for (int mi = 0; mi < 8; ++mi) {
        const int mrow = m_base + wm * 128 + mi * 16 + quad * 4;
        float bias[4];
        #pragma unroll
        for (int r = 0; r < 4; ++r) bias[r] = bfs[mrow + r];
        #pragma unroll
        for (int ni = 0; ni < 4; ++ni) {
            const int ng = n_base + wn * 64 + ni * 16 + l16;
            f32x4 a = acc[mi][ni];
            u16 o0 = f2bf(fmaxf(a[0] + bias[0], 0.f));
            u16 o1 = f2bf(fmaxf(a[1] + bias[1], 0.f));
            u16 o2 = f2bf(fmaxf(a[2] + bias[2], 0.f));
            u16 o3 = f2bf(fmaxf(a[3] + bias[3], 0.f));
            uint2 pv;
            pv.x = (u32)o0 | ((u32)o1 << 16);
            pv.y = (u32)o2 | ((u32)o3 << 16);
            *(uint2*)&y[(long)ng * 512 + mrow] = pv;
        }
    }
}

// ---------------------------------------------------------------- fused pools
__device__ __forceinline__ uint4 max8(uint4 A, uint4 Bv)
{
    const u16* a = (const u16*)&A;
    const u16* b = (const u16*)&Bv;
    uint4 R;
    u16* r = (u16*)&R;
    #pragma unroll
    for (int i = 0; i < 8; ++i) r[i] = (bf2f(a[i]) >= bf2f(b[i])) ? a[i] : b[i];
    return R;
}

// One thread owns (b,hw,c8): loads 16 t-slices, computes all four temporal
// pools via a sliding-max tree in registers, writes 13+9+5+1 outputs.
// Reads y exactly once (25.7 MB) vs ~130 MB for the old two-kernel chain.
__global__ void pool_all(const u16* __restrict__ y, u16* __restrict__ p4,
                         u16* __restrict__ p8, u16* __restrict__ p12,
                         u16* __restrict__ p16)
{
    int g = blockIdx.x * 256 + threadIdx.x;
    if (g >= 100352) return;                 // 2*784*64
    const int c8 = g & 63;
    int pos = g >> 6;
    const int hw = pos % 784; const int b = pos / 784;
    const u16* src = y + ((long)(b * 16) * 784 + hw) * 512 + c8 * 8;
    uint4 v[16];
    #pragma unroll
    for (int t = 0; t < 16; ++t)
        v[t] = *(const uint4*)(src + (long)t * 401408);
    uint4 pr[15];
    #pragma unroll
    for (int t = 0; t < 15; ++t) pr[t] = max8(v[t], v[t + 1]);
    uint4 qd[13];
    #pragma unroll
    for (int t = 0; t < 13; ++t) qd[t] = max8(pr[t], pr[t + 2]);
    uint4 e8[9];
    #pragma unroll
    for (int t = 0; t < 9; ++t) e8[t] = max8(qd[t], qd[t + 4]);
    uint4 e12[5];
    #pragma unroll
    for (int t = 0; t < 5; ++t) e12[t] = max8(e8[t], qd[t + 8]);
    uint4 e16 = max8(e8[0], e8[8]);

    const long col = (long)hw * 512 + c8 * 8;
    #pragma unroll
    for (int t = 0; t < 13; ++t)
        *(uint4*)&p4[((long)(b * 13 + t) * 784) * 512 + col] = qd[t];
    #pragma unroll
    for (int t = 0; t < 9; ++t)
        *(uint4*)&p8[((long)(b * 9 + t) * 784) * 512 + col] = e8[t];
    #pragma unroll
    for (int t = 0; t < 5; ++t)
        *(uint4*)&p12[((long)(b * 5 + t) * 784) * 512 + col] = e12[t];
    *(uint4*)&p16[((long)b * 784) * 512 + col] = e16;
}

// ---------------------------------------------------------------- fused heads GEMM
// Ring-2 LDS (64 KiB), single barrier + counted-vmcnt per K-step (conv R6
// schedule): {vmcnt(0) gate (nothing newer in flight -> exact); s_barrier;
// 16 ds_reads; stage next tile into other buffer; setprio 32 MFMA}.
__global__ __launch_bounds__(256, 2) void heads_gemm(
    const u16* __restrict__ p16, const u16* __restrict__ p12,
    const u16* __restrict__ p8,  const u16* __restrict__ p4,
    const u16* __restrict__ wcls, const u16* __restrict__ wb1,
    const u16* __restrict__ wb34, const u16* __restrict__ wb2,
    const u16* __restrict__ wb4,  const float* __restrict__ bfs,
    float* __restrict__ clsr, void* __restrict__ outv,
    const u32* __restrict__ im)
{
    const int f32 = is_f32(im);
    int bid = blockIdx.x;
    const u16* pool; const u16* wbp; int Ti, CH, nt, mt; long boff, coff, ooff;
    if (bid < 104)      {             nt = bid % 13;  mt = bid / 13;  pool = p16; wbp = wb1;  Ti = 1;  CH = 960; boff = 542;  coff = 0;      ooff = 1317120; }
    else if (bid < 476) { bid -= 104; nt = bid % 62;  mt = bid / 62;  pool = p12; wbp = wb34; Ti = 5;  CH = 720; boff = 1502; coff = 47040;  ooff = 2822400; }
    else if (bid < 920) { bid -= 476; nt = bid % 111; mt = bid / 111; pool = p8;  wbp = wb2;  Ti = 9;  CH = 480; boff = 2222; coff = 282240; ooff = 8467200; }
    else                { bid -= 920; nt = bid % 160; mt = bid / 160; pool = p4;  wbp = wb4;  Ti = 13; CH = 240; boff = 2702; coff = 705600; ooff = 15240960; }
    const int M = 30 + CH;
    const int THW = Ti * 784;
    const int N = 2 * THW;
    const int n_base = nt * 128;
    const int m_base = mt * 128;

    __shared__ u16 lds[32768];               // 2 bufs x (A 8192 + B 8192)
    const int tid = threadIdx.x;
    const int lane = tid & 63;
    const int wid  = tid >> 6;
    const int quad = lane >> 4;
    const int l16  = lane & 15;
    const int wm = (wid & 1) * 64;
    const int wn = (wid >> 1) * 64;
    const int srow = tid >> 3;
    const int lc8  = ((tid & 7) ^ (srow & 7)) * 8;

    const u16* arow[4]; const u16* brow[4];
    #pragma unroll
    for (int j = 0; j < 4; ++j) {
        int m = m_base + j * 32 + srow; if (m > M - 1) m = M - 1;
        arow[j] = ((m < 30) ? (wcls + m * 512) : (wbp + (m - 30) * 512)) + lc8;
        int n = n_base + j * 32 + srow; if (n > N - 1) n = N - 1;
        brow[j] = pool + (long)n * 512 + lc8;
    }

    int rowA[4], rowB[4];
    #pragma unroll
    for (int i = 0; i < 4; ++i) {
        rowA[i] = (wm + i * 16 + l16) * 64;
        rowB[i] = 8192 + (wn + i * 16 + l16) * 64;
    }
    const int cx  = l16 & 7;
    const int ch0 = (quad ^ cx) * 8;
    const int ch1 = ((4 + quad) ^ cx) * 8;

    // prologue: stage K-step 0 into buf 0
    #pragma unroll
    for (int j = 0; j < 4; ++j)
        gl2lds16(arow[j], &lds[tid * 8 + j * 2048]);
    #pragma unroll
    for (int j = 0; j < 4; ++j)
        gl2lds16(brow[j], &lds[8192 + tid * 8 + j * 2048]);

    f32x4 acc[4][4] = {};
    for (int kc = 0; kc < 8; ++kc) {
        asm volatile("s_waitcnt vmcnt(0)" ::: "memory");
        asm volatile("s_barrier" ::: "memory");
        const u16* buf = lds + (kc & 1) * 16384;
        bf16x8 af[8], bfr[8];
        #pragma unroll
        for (int mi = 0; mi < 4; ++mi) {
            af[mi]     = *(const bf16x8*)&buf[rowA[mi] + ch0];
            af[mi + 4] = *(const bf16x8*)&buf[rowA[mi] + ch1];
        }
        #pragma unroll
        for (int ni = 0; ni < 4; ++ni) {
            bfr[ni]     = *(const bf16x8*)&buf[rowB[ni] + ch0];
            bfr[ni + 4] = *(const bf16x8*)&buf[rowB[ni] + ch1];
        }
        if (kc < 7) {
            u16* dst = lds + ((kc + 1) & 1) * 16384 + tid * 8;
            const int kcol = (kc + 1) * 64;
            #pragma unroll
            for (int j = 0; j < 4; ++j)
                gl2lds16(arow[j] + kcol, dst + j * 2048);
            #pragma unroll
            for (int j = 0; j < 4; ++j)
                gl2lds16(brow[j] + kcol, dst + 8192 + j * 2048);
        }
        __builtin_amdgcn_s_setprio(1);
        #pragma unroll
        for (int mi = 0; mi < 4; ++mi)
            #pragma unroll
            for (int ni = 0; ni < 4; ++ni)
                acc[mi][ni] = __builtin_amdgcn_mfma_f32_16x16x32_bf16(
                    af[mi], bfr[ni], acc[mi][ni], 0, 0, 0);
        #pragma unroll
        for (int mi = 0; mi < 4; ++mi)
            #pragma unroll
            for (int ni = 0; ni < 4; ++ni)
                acc[mi][ni] = __builtin_amdgcn_mfma_f32_16x16x32_bf16(
                    af[mi + 4], bfr[ni + 4], acc[mi][ni], 0, 0, 0);
        __builtin_amdgcn_s_setprio(0);
    }

    const float* bcls = bfs + 512;
    const float* bb   = bfs + boff;
    #pragma unroll
    for (int mi = 0; mi < 4; ++mi) {
        const int mrow = m_base + wm + mi * 16 + quad * 4;
        #pragma unroll
        for (int ni = 0; ni < 4; ++ni) {
            const int ng = n_base + wn + ni * 16 + l16;
            if (ng >= N) continue;
            const int b  = ng / THW;
            const int rr = ng % THW;
            f32x4 a = acc[mi][ni];
            #pragma unroll
            for (int r = 0; r < 4; ++r) {
                const int m = mrow + r;
                if (m >= M) break;
                const float bias = (m < 30) ? bcls[m] : bb[m - 30];
                const float v = a[r] + bias;
                if (m < 30) {
                    clsr[coff + ((long)(b * 30 + m)) * THW + rr] = v;
                } else {
                    const long oi = ooff + ((long)(b * CH + (m - 30))) * THW + rr;
                    if (f32) ((float*)outv)[oi] = v;
                    else     ((u16*)outv)[oi]   = f2bf(v);
                }
            }
        }
    }
}

// ---------------------------------------------------------------- pair softmax
__global__ void softmax_all(const float* __restrict__ clsr,
                            void* __restrict__ outv, const u32* __restrict__ im)
{
    const int f32 = is_f32(im);
    int g = blockIdx.x * 256 + threadIdx.x;
    if (g >= 658560) return;
    int Ti; long off;
    if      (g < 23520)  { Ti = 1;  off = 0; }
    else if (g < 141120) { Ti = 5;  off = 47040;  g -= 23520; }
    else if (g < 352800) { Ti = 9;  off = 282240; g -= 141120; }
    else                 { Ti = 13; off = 705600; g -= 352800; }
    const int THW = Ti * 784;
    const int rr = g % THW;
    int r2 = g / THW;
    const int j = r2 % 15; const int b = r2 / 15;
    const long i0 = off + ((long)(b * 30 + j)) * THW + rr;
    const long i1 = off + ((long)(b * 30 + j + 15)) * THW + rr;
    const float s0 = clsr[i0], s1 = clsr[i1];
    const float mx = fmaxf(s0, s1);
    const float e0 = __expf(s0 - mx), e1 = __expf(s1 - mx);
    const float inv = 1.0f / (e0 + e1);
    if (f32) {
        ((float*)outv)[i0] = e0 * inv;
        ((float*)outv)[i1] = e1 * inv;
    } else {
        ((u16*)outv)[i0] = f2bf(e0 * inv);
        ((u16*)outv)[i1] = f2bf(e1 * inv);
    }
}

// ---------------------------------------------------------------- launcher
extern "C" void kernel_launch(void* const* d_in, const int* in_sizes, int n_in,
                              void* d_out, int out_size, void* d_ws, size_t ws_size,
                              hipStream_t stream)
{
    const void* base_feat = d_in[0];
    const u32*  im_info   = (const u32*)d_in[1];
    const void* W_conv    = d_in[4];
    const void* b_conv    = d_in[5];
    const void* W_cls     = d_in[6];
    const void* b_cls     = d_in[7];
    const void* W_bbox    = d_in[8];
    const void* b_bbox    = d_in[9];
    const void* W_bbox34  = d_in[10];
    const void* b_bbox34  = d_in[11];
    const void* W_bbox2   = d_in[12];
    const void* b_bbox2   = d_in[13];
    const void* W_bbox4   = d_in[14];
    const void* b_bbox4   = d_in[15];

    char* ws = (char*)d_ws;
    u16*   xpad = (u16*)  (ws + 0);           // 33,177,600
    u16*   wt   = (u16*)  (ws + 33177600);    // 14,155,776 -> 47,333,376
    u16*   y    = (u16*)  (ws + 47333376);    // 25,690,112 -> 73,023,488
    u16*   p4   = (u16*)  (ws + 73023488);    // 20,873,216 -> 93,896,704
    u16*   p8   = (u16*)  (ws + 93896704);    // 14,450,688 -> 108,347,392
    u16*   p12  = (u16*)  (ws + 108347392);   //  8,028,160 -> 116,375,552
    u16*   p16  = (u16*)  (ws + 116375552);   //  1,605,632 -> 117,981,184
    float* clsr = (float*)(ws + 117981184);   //  5,268,480 -> 123,249,664
    u16*   whd  = (u16*)  (ws + 123249728);   //  2,488,320 -> 125,738,048
    float* bfs  = (float*)(ws + 125738048);   //     11,768

    u16* w_cls_b  = whd;
    u16* w_b1_b   = whd + 15360;
    u16* w_b34_b  = whd + 506880;
    u16* w_b2_b   = whd + 875520;
    u16* w_b4_b   = whd + 1121280;

    zero_kernel<<<8100, 256, 0, stream>>>((uint4*)xpad, 2073600);
    pad_fill<<<7168, 256, 0, stream>>>(base_feat, xpad, im_info);
    wt_transform<<<1024, 256, 0, stream>>>(W_conv, wt, im_info);
    cvt_all<<<4873, 256, 0, stream>>>(W_cls, W_bbox, W_bbox34, W_bbox2, W_bbox4,
                                      b_conv, b_cls, b_bbox, b_bbox34, b_bbox2,
                                      b_bbox4, whd, bfs, im_info);

    conv_gemm256<<<196, 512, 0, stream>>>(xpad, wt, bfs, y);

    pool_all<<<392, 256, 0, stream>>>(y, p4, p8, p12, p16);

    heads_gemm<<<1400, 256, 0, stream>>>(p16, p12, p8, p4,
                                         w_cls_b, w_b1_b, w_b34_b, w_b2_b, w_b4_b,
                                         bfs, clsr, d_out, im_info);

    softmax_all<<<2573, 256, 0, stream>>>(clsr, d_out, im_info);
}

// Round 4
// 571.616 us; speedup vs baseline: 1.0890x; 1.0890x over previous
//
#include <hip/hip_runtime.h>

typedef unsigned short u16;
typedef unsigned int   u32;
typedef __bf16  bf16x8 __attribute__((ext_vector_type(8)));
typedef float   f32x4  __attribute__((ext_vector_type(4)));

__device__ __forceinline__ float bf2f(u16 u) {
    u32 v = ((u32)u) << 16;
    return __builtin_bit_cast(float, v);
}
__device__ __forceinline__ u16 f2bf(float f) {
    u32 u = __builtin_bit_cast(u32, f);
    return (u16)((u + 0x7FFFu + ((u >> 16) & 1u)) >> 16);   // RNE
}
__device__ __forceinline__ float ldf(const void* p, long i, int f32) {
    return f32 ? ((const float*)p)[i] : bf2f(((const u16*)p)[i]);
}
__device__ __forceinline__ int is_f32(const u32* im) {
    return im[0] == 0x43E00000u;   // 448.0f fp32 vs packed bf16 (0x43E043E0)
}
// async global->LDS, 16B per lane (LDS dst = wave-uniform base + lane*16)
__device__ __forceinline__ void gl2lds16(const u16* g, u16* l) {
    __builtin_amdgcn_global_load_lds(
        (const __attribute__((address_space(1))) void*)g,
        (__attribute__((address_space(3))) void*)l, 16, 0, 0);
}

// ---------------------------------------------------------------- zero (xpad)
__global__ void zero_kernel(uint4* __restrict__ p, const int n)
{
    int i = blockIdx.x * 256 + threadIdx.x;
    if (i < n) p[i] = uint4{0u, 0u, 0u, 0u};
}

// ------------------------------------------------- pad+transpose base_feat
__global__ void pad_fill(const void* __restrict__ src, u16* __restrict__ xpad,
                         const u32* __restrict__ im)
{
    const int f32 = is_f32(im);
    __shared__ u16 lds[56 * 40];
    int blk = blockIdx.x;
    const int h2  = blk % 14;  blk /= 14;
    const int c32 = blk & 15;  blk >>= 4;
    const int t   = blk & 15;
    const int b   = blk >> 4;
    const int tid = threadIdx.x;
    const long sbase = ((long)(b * 512 + c32 * 32) * 16 + t) * 784 + h2 * 56;
    #pragma unroll
    for (int it = tid; it < 1792; it += 256) {
        const int c = it / 56, p = it - c * 56;
        float v = f32 ? ((const float*)src)[sbase + (long)c * 12544 + p]
                      : bf2f(((const u16*)src)[sbase + (long)c * 12544 + p]);
        lds[p * 40 + c] = f2bf(v);
    }
    __syncthreads();
    if (tid < 224) {
        const int p = tid >> 2, g = tid & 3;
        const int h = h2 * 2 + p / 28, w = p % 28;
        const long o = (((long)(b * 18 + t + 1) * 30 + h + 1) * 30 + (w + 1)) * 512
                       + c32 * 32 + g * 8;
        *(uint4*)&xpad[o] = *(const uint4*)&lds[p * 40 + g * 8];
    }
}

// ------------------------------------------------- W_conv [O][I][27] -> Wt[27][O][I]
__global__ void wt_transform(const void* __restrict__ wconv, u16* __restrict__ wt,
                             const u32* __restrict__ im)
{
    const int f32 = is_f32(im);
    __shared__ u16 lds[256 * 28];
    const int tid = threadIdx.x;
    const int pair_base = blockIdx.x * 256;
    const long s0 = (long)pair_base * 27;
    for (int it = tid; it < 256 * 27; it += 256) {
        const int p = it / 27, o = it - p * 27;
        float v = f32 ? ((const float*)wconv)[s0 + it]
                      : bf2f(((const u16*)wconv)[s0 + it]);
        lds[p * 28 + o] = f2bf(v);
    }
    __syncthreads();
    #pragma unroll
    for (int off = 0; off < 27; ++off)
        wt[(long)off * 262144 + pair_base + tid] = lds[tid * 28 + off];
}

// ------------------------------------------------- head weights + biases (merged)
__global__ void cvt_all(const void* s0, const void* s1, const void* s2,
                        const void* s3, const void* s4,
                        const void* b0, const void* b1, const void* b2,
                        const void* b3, const void* b4, const void* b5,
                        u16* __restrict__ whd, float* __restrict__ bfs,
                        const u32* __restrict__ im)
{
    const int f32 = is_f32(im);
    int i = blockIdx.x * 256 + threadIdx.x;
    if (i < 1244160) {
        const void* s; long j;
        if      (i < 15360)   { s = s0; j = i; }
        else if (i < 506880)  { s = s1; j = i - 15360; }
        else if (i < 875520)  { s = s2; j = i - 506880; }
        else if (i < 1121280) { s = s3; j = i - 875520; }
        else                  { s = s4; j = i - 1121280; }
        whd[i] = f2bf(ldf(s, j, f32));
        return;
    }
    i -= 1244160;
    if (i >= 2942) return;
    float v;
    if      (i < 512)  v = ldf(b0, i, f32);
    else if (i < 542)  v = ldf(b1, i - 512, f32);
    else if (i < 1502) v = ldf(b2, i - 542, f32);
    else if (i < 2222) v = ldf(b3, i - 1502, f32);
    else if (i < 2702) v = ldf(b4, i - 2222, f32);
    else               v = ldf(b5, i - 2702, f32);
    bfs[i] = v;
}

// ---------------------------------------------------------------- conv GEMM (R6)
// 256x256 tile, BK=32, ring-4 LDS (128 KiB), SINGLE barrier per K-tile:
//   vmcnt(gate) ; s_barrier ; 12 ds_read_b128 ; 4 gl2lds stages ; 32 MFMA.
__global__ __launch_bounds__(512, 2) void conv_gemm256(
    const u16* __restrict__ xpad, const u16* __restrict__ wt,
    const float* __restrict__ bfs, u16* __restrict__ y)
{
    __shared__ u16 smem[65536];           // 4 bufs x (A 8192 + B 8192) u16
    const int tid = threadIdx.x;

    // bijective XCD remap (m204, nwg=196), pair-major so (n,m0),(n,m1) co-XCD
    const int bx  = blockIdx.x;
    const int xcd = bx & 7, pos = bx >> 3;
    const int L   = (xcd < 4 ? xcd * 25 : 100 + (xcd - 4) * 24) + pos;
    const int m_base = (L & 1) * 256;
    const int n_base = (L >> 1) * 256;

    const int rq  = tid >> 2;                                  // 0..127
    const int gsw = (((tid & 3) ^ ((tid >> 3) & 3))) * 8;      // elems
    const u16* pa0 = wt + (long)(m_base + rq) * 512 + gsw;
    const u16* pa1 = pa0 + 128 * 512;

    const int n0 = n_base + rq;
    const int n1 = n0 + 128;
    int b0 = n0 / 12544, r0 = n0 % 12544;
    int t0 = r0 / 784,   q0 = r0 % 784;
    int h0 = q0 / 28,    w0 = q0 % 28;
    int b1 = n1 / 12544, r1 = n1 % 12544;
    int t1 = r1 / 784,   q1 = r1 % 784;
    int h1 = q1 / 28,    w1 = q1 % 28;
    const int sa0 = ((b0 * 18 + t0) * 30 + h0) * 30 + w0;
    const int sa1 = ((b1 * 18 + t1) * 30 + h1) * 30 + w1;
    const u16* pb0 = xpad + (long)sa0 * 512 + gsw;
    const u16* pb1 = xpad + (long)sa1 * 512 + gsw;

    const int lane = tid & 63, wid = tid >> 6;
    const int l16 = lane & 15, quad = lane >> 4;
    const int wm = wid >> 2;              // 0..1 -> 128 rows
    const int wn = wid & 3;               // 0..3 -> 64 cols
    const int slot  = (quad ^ ((l16 >> 1) & 3)) * 8;
    const int aoffs = (wm * 128 + l16) * 32 + slot;            // + mi*512
    const int boffs = 8192 + (wn * 64 + l16) * 32 + slot;      // + ni*512

    f32x4 acc[8][4] = {};

    // prologue: stage K-tiles 0..2 (12 gl2lds in flight)
    #pragma unroll
    for (int k = 0; k < 3; ++k) {
        u16* dst = smem + (k << 14);
        gl2lds16(pa0 + k * 32, dst + tid * 8);
        gl2lds16(pa1 + k * 32, dst + 4096  + tid * 8);
        gl2lds16(pb0 + k * 32, dst + 8192  + tid * 8);
        gl2lds16(pb1 + k * 32, dst + 12288 + tid * 8);
    }

#define KTILE(ktl, STG, GATE)                                                  \
    {                                                                          \
        asm volatile("s_waitcnt vmcnt(" #GATE ")" ::: "memory");               \
        asm volatile("s_barrier" ::: "memory");                                \
        const u16* buf = smem + (((ktl) & 3) << 14);                           \
        bf16x8 af[8], bfr[4];                                                  \
        _Pragma("unroll")                                                      \
        for (int mi = 0; mi < 4; ++mi)                                         \
            af[mi] = *(const bf16x8*)&buf[aoffs + mi * 512];                   \
        _Pragma("unroll")                                                      \
        for (int ni = 0; ni < 4; ++ni)                                         \
            bfr[ni] = *(const bf16x8*)&buf[boffs + ni * 512];                  \
        _Pragma("unroll")                                                      \
        for (int mi = 4; mi < 8; ++mi)                                         \
            af[mi] = *(const bf16x8*)&buf[aoffs + mi * 512];                   \
        if (STG) {                                                             \
            const int kts = (ktl) + 3;                                         \
            const int tap = kts >> 4, kc = kts & 15;                           \
            const int kd = tap / 9, r9 = tap - kd * 9;                         \
            const int kh = r9 / 3,  kw = r9 - kh * 3;                          \
            const long aoff = (long)tap * 262144 + kc * 32;                    \
            const long boff = (long)(kd * 900 + kh * 30 + kw) * 512 + kc * 32; \
            u16* dst = smem + ((kts & 3) << 14);                               \
            gl2lds16(pa0 + aoff, dst + tid * 8);                               \
            gl2lds16(pa1 + aoff, dst + 4096  + tid * 8);                       \
            gl2lds16(pb0 + boff, dst + 8192  + tid * 8);                       \
            gl2lds16(pb1 + boff, dst + 12288 + tid * 8);                       \
        }                                                                      \
        __builtin_amdgcn_s_setprio(1);                                         \
        _Pragma("unroll")                                                      \
        for (int mi = 0; mi < 4; ++mi)                                         \
            _Pragma("unroll")                                                  \
            for (int ni = 0; ni < 4; ++ni)                                     \
                acc[mi][ni] = __builtin_amdgcn_mfma_f32_16x16x32_bf16(         \
                    af[mi], bfr[ni], acc[mi][ni], 0, 0, 0);                    \
        _Pragma("unroll")                                                      \
        for (int mi = 4; mi < 8; ++mi)                                         \
            _Pragma("unroll")                                                  \
            for (int ni = 0; ni < 4; ++ni)                                     \
                acc[mi][ni] = __builtin_amdgcn_mfma_f32_16x16x32_bf16(         \
                    af[mi], bfr[ni], acc[mi][ni], 0, 0, 0);                    \
        __builtin_amdgcn_s_setprio(0);                                         \
    }

    for (int kt = 0; kt < 429; ++kt) KTILE(kt, 1, 8)
    KTILE(429, 0, 8)
    KTILE(430, 0, 4)
    KTILE(431, 0, 0)
#undef KTILE

    // epilogue: bias + relu + bf16 store to y[n][512]
    #pragma unroll
    for (int mi = 0; mi < 8; ++mi) {
        const int mrow = m_base + wm * 128 + mi * 16 + quad * 4;
        float bias[4];
        #pragma unroll
        for (int r = 0; r < 4; ++r) bias[r] = bfs[mrow + r];
        #pragma unroll
        for (int ni = 0; ni < 4; ++ni) {
            const int ng = n_base + wn * 64 + ni * 16 + l16;
            f32x4 a = acc[mi][ni];
            u16 o0 = f2bf(fmaxf(a[0] + bias[0], 0.f));
            u16 o1 = f2bf(fmaxf(a[1] + bias[1], 0.f));
            u16 o2 = f2bf(fmaxf(a[2] + bias[2], 0.f));
            u16 o3 = f2bf(fmaxf(a[3] + bias[3], 0.f));
            uint2 pv;
            pv.x = (u32)o0 | ((u32)o1 << 16);
            pv.y = (u32)o2 | ((u32)o3 << 16);
            *(uint2*)&y[(long)ng * 512 + mrow] = pv;
        }
    }
}

// ---------------------------------------------------------------- fused pools
__device__ __forceinline__ uint2 max4(uint2 A, uint2 Bv)
{
    const u16* a = (const u16*)&A;
    const u16* b = (const u16*)&Bv;
    uint2 R;
    u16* r = (u16*)&R;
    #pragma unroll
    for (int i = 0; i < 4; ++i) r[i] = (bf2f(a[i]) >= bf2f(b[i])) ? a[i] : b[i];
    return R;
}

// One thread owns (b,hw,c4): loads 16 t-slices (uint2 = 4 bf16), computes all
// four temporal pools via a sliding-max tree in registers, writes 13+9+5+1
// outputs. Reads y exactly once (25.7 MB). uint2 granularity -> 200704
// threads / 784 blocks for TLP (R3's uint4 version had only 392 blocks and
// ~130 live VGPRs -> latency-bound).
__global__ void pool_all(const u16* __restrict__ y, u16* __restrict__ p4,
                         u16* __restrict__ p8, u16* __restrict__ p12,
                         u16* __restrict__ p16)
{
    int g = blockIdx.x * 256 + threadIdx.x;
    if (g >= 200704) return;                 // 2*784*128
    const int c4 = g & 127;
    int pos = g >> 7;
    const int hw = pos % 784; const int b = pos / 784;
    const u16* src = y + ((long)(b * 16) * 784 + hw) * 512 + c4 * 4;
    uint2 v[16];
    #pragma unroll
    for (int t = 0; t < 16; ++t)
        v[t] = *(const uint2*)(src + (long)t * 401408);
    uint2 pr[15];
    #pragma unroll
    for (int t = 0; t < 15; ++t) pr[t] = max4(v[t], v[t + 1]);
    uint2 qd[13];
    #pragma unroll
    for (int t = 0; t < 13; ++t) qd[t] = max4(pr[t], pr[t + 2]);
    uint2 e8[9];
    #pragma unroll
    for (int t = 0; t < 9; ++t) e8[t] = max4(qd[t], qd[t + 4]);
    uint2 e12[5];
    #pragma unroll
    for (int t = 0; t < 5; ++t) e12[t] = max4(e8[t], qd[t + 8]);
    uint2 e16 = max4(e8[0], e8[8]);

    const long col = (long)hw * 512 + c4 * 4;
    #pragma unroll
    for (int t = 0; t < 13; ++t)
        *(uint2*)&p4[((long)(b * 13 + t) * 784) * 512 + col] = qd[t];
    #pragma unroll
    for (int t = 0; t < 9; ++t)
        *(uint2*)&p8[((long)(b * 9 + t) * 784) * 512 + col] = e8[t];
    #pragma unroll
    for (int t = 0; t < 5; ++t)
        *(uint2*)&p12[((long)(b * 5 + t) * 784) * 512 + col] = e12[t];
    *(uint2*)&p16[((long)b * 784) * 512 + col] = e16;
}

// ---------------------------------------------------------------- fused heads GEMM
// BK=64 (8 K-steps), XOR-swizzled LDS staging. (R2-proven version.)
__global__ __launch_bounds__(256, 2) void heads_gemm(
    const u16* __restrict__ p16, const u16* __restrict__ p12,
    const u16* __restrict__ p8,  const u16* __restrict__ p4,
    const u16* __restrict__ wcls, const u16* __restrict__ wb1,
    const u16* __restrict__ wb34, const u16* __restrict__ wb2,
    const u16* __restrict__ wb4,  const float* __restrict__ bfs,
    float* __restrict__ clsr, void* __restrict__ outv,
    const u32* __restrict__ im)
{
    const int f32 = is_f32(im);
    int bid = blockIdx.x;
    const u16* pool; const u16* wbp; int Ti, CH, nt, mt; long boff, coff, ooff;
    if (bid < 104)      {             nt = bid % 13;  mt = bid / 13;  pool = p16; wbp = wb1;  Ti = 1;  CH = 960; boff = 542;  coff = 0;      ooff = 1317120; }
    else if (bid < 476) { bid -= 104; nt = bid % 62;  mt = bid / 62;  pool = p12; wbp = wb34; Ti = 5;  CH = 720; boff = 1502; coff = 47040;  ooff = 2822400; }
    else if (bid < 920) { bid -= 476; nt = bid % 111; mt = bid / 111; pool = p8;  wbp = wb2;  Ti = 9;  CH = 480; boff = 2222; coff = 282240; ooff = 8467200; }
    else                { bid -= 920; nt = bid % 160; mt = bid / 160; pool = p4;  wbp = wb4;  Ti = 13; CH = 240; boff = 2702; coff = 705600; ooff = 15240960; }
    const int M = 30 + CH;
    const int THW = Ti * 784;
    const int N = 2 * THW;
    const int n_base = nt * 128;
    const int m_base = mt * 128;

    __shared__ u16 lds_a[128 * 64];
    __shared__ u16 lds_b[128 * 64];
    const int tid = threadIdx.x;
    const int lane = tid & 63;
    const int wid  = tid >> 6;
    const int quad = lane >> 4;
    const int l16  = lane & 15;
    const int wm = (wid & 1) * 64;
    const int wn = (wid >> 1) * 64;
    const int srow = tid >> 3;
    const int lc8  = ((tid & 7) ^ (srow & 7)) * 8;

    const u16* arow[4]; const u16* brow[4];
    #pragma unroll
    for (int j = 0; j < 4; ++j) {
        int m = m_base + j * 32 + srow; if (m > M - 1) m = M - 1;
        arow[j] = ((m < 30) ? (wcls + m * 512) : (wbp + (m - 30) * 512)) + lc8;
        int n = n_base + j * 32 + srow; if (n > N - 1) n = N - 1;
        brow[j] = pool + (long)n * 512 + lc8;
    }

    u16* ldst_a = &lds_a[tid * 8];
    u16* ldst_b = &lds_b[tid * 8];

    int rowA[4], rowB[4];
    #pragma unroll
    for (int i = 0; i < 4; ++i) {
        rowA[i] = (wm + i * 16 + l16) * 64;
        rowB[i] = (wn + i * 16 + l16) * 64;
    }
    const int cx  = l16 & 7;
    const int ch0 = (quad ^ cx) * 8;
    const int ch1 = ((4 + quad) ^ cx) * 8;

    f32x4 acc[4][4] = {};
    for (int kc = 0; kc < 8; ++kc) {
        const int kcol = kc * 64;
        #pragma unroll
        for (int j = 0; j < 4; ++j)
            gl2lds16(arow[j] + kcol, ldst_a + j * 2048);
        #pragma unroll
        for (int j = 0; j < 4; ++j)
            gl2lds16(brow[j] + kcol, ldst_b + j * 2048);
        __syncthreads();
        #pragma unroll
        for (int h = 0; h < 2; ++h) {
            const int co = h ? ch1 : ch0;
            bf16x8 af[4], bfr[4];
            #pragma unroll
            for (int mi = 0; mi < 4; ++mi)
                af[mi]  = *(const bf16x8*)&lds_a[rowA[mi] + co];
            #pragma unroll
            for (int ni = 0; ni < 4; ++ni)
                bfr[ni] = *(const bf16x8*)&lds_b[rowB[ni] + co];
            #pragma unroll
            for (int mi = 0; mi < 4; ++mi)
                #pragma unroll
                for (int ni = 0; ni < 4; ++ni)
                    acc[mi][ni] = __builtin_amdgcn_mfma_f32_16x16x32_bf16(
                        af[mi], bfr[ni], acc[mi][ni], 0, 0, 0);
        }
        __syncthreads();
    }
    const float* bcls = bfs + 512;
    const float* bb   = bfs + boff;
    #pragma unroll
    for (int mi = 0; mi < 4; ++mi) {
        const int mrow = m_base + wm + mi * 16 + quad * 4;
        #pragma unroll
        for (int ni = 0; ni < 4; ++ni) {
            const int ng = n_base + wn + ni * 16 + l16;
            if (ng >= N) continue;
            const int b  = ng / THW;
            const int rr = ng % THW;
            f32x4 a = acc[mi][ni];
            #pragma unroll
            for (int r = 0; r < 4; ++r) {
                const int m = mrow + r;
                if (m >= M) break;
                const float bias = (m < 30) ? bcls[m] : bb[m - 30];
                const float v = a[r] + bias;
                if (m < 30) {
                    clsr[coff + ((long)(b * 30 + m)) * THW + rr] = v;
                } else {
                    const long oi = ooff + ((long)(b * CH + (m - 30))) * THW + rr;
                    if (f32) ((float*)outv)[oi] = v;
                    else     ((u16*)outv)[oi]   = f2bf(v);
                }
            }
        }
    }
}

// ---------------------------------------------------------------- pair softmax
__global__ void softmax_all(const float* __restrict__ clsr,
                            void* __restrict__ outv, const u32* __restrict__ im)
{
    const int f32 = is_f32(im);
    int g = blockIdx.x * 256 + threadIdx.x;
    if (g >= 658560) return;
    int Ti; long off;
    if      (g < 23520)  { Ti = 1;  off = 0; }
    else if (g < 141120) { Ti = 5;  off = 47040;  g -= 23520; }
    else if (g < 352800) { Ti = 9;  off = 282240; g -= 141120; }
    else                 { Ti = 13; off = 705600; g -= 352800; }
    const int THW = Ti * 784;
    const int rr = g % THW;
    int r2 = g / THW;
    const int j = r2 % 15; const int b = r2 / 15;
    const long i0 = off + ((long)(b * 30 + j)) * THW + rr;
    const long i1 = off + ((long)(b * 30 + j + 15)) * THW + rr;
    const float s0 = clsr[i0], s1 = clsr[i1];
    const float mx = fmaxf(s0, s1);
    const float e0 = __expf(s0 - mx), e1 = __expf(s1 - mx);
    const float inv = 1.0f / (e0 + e1);
    if (f32) {
        ((float*)outv)[i0] = e0 * inv;
        ((float*)outv)[i1] = e1 * inv;
    } else {
        ((u16*)outv)[i0] = f2bf(e0 * inv);
        ((u16*)outv)[i1] = f2bf(e1 * inv);
    }
}

// ---------------------------------------------------------------- launcher
extern "C" void kernel_launch(void* const* d_in, const int* in_sizes, int n_in,
                              void* d_out, int out_size, void* d_ws, size_t ws_size,
                              hipStream_t stream)
{
    const void* base_feat = d_in[0];
    const u32*  im_info   = (const u32*)d_in[1];
    const void* W_conv    = d_in[4];
    const void* b_conv    = d_in[5];
    const void* W_cls     = d_in[6];
    const void* b_cls     = d_in[7];
    const void* W_bbox    = d_in[8];
    const void* b_bbox    = d_in[9];
    const void* W_bbox34  = d_in[10];
    const void* b_bbox34  = d_in[11];
    const void* W_bbox2   = d_in[12];
    const void* b_bbox2   = d_in[13];
    const void* W_bbox4   = d_in[14];
    const void* b_bbox4   = d_in[15];

    char* ws = (char*)d_ws;
    u16*   xpad = (u16*)  (ws + 0);           // 33,177,600
    u16*   wt   = (u16*)  (ws + 33177600);    // 14,155,776 -> 47,333,376
    u16*   y    = (u16*)  (ws + 47333376);    // 25,690,112 -> 73,023,488
    u16*   p4   = (u16*)  (ws + 73023488);    // 20,873,216 -> 93,896,704
    u16*   p8   = (u16*)  (ws + 93896704);    // 14,450,688 -> 108,347,392
    u16*   p12  = (u16*)  (ws + 108347392);   //  8,028,160 -> 116,375,552
    u16*   p16  = (u16*)  (ws + 116375552);   //  1,605,632 -> 117,981,184
    float* clsr = (float*)(ws + 117981184);   //  5,268,480 -> 123,249,664
    u16*   whd  = (u16*)  (ws + 123249728);   //  2,488,320 -> 125,738,048
    float* bfs  = (float*)(ws + 125738048);   //     11,768

    u16* w_cls_b  = whd;
    u16* w_b1_b   = whd + 15360;
    u16* w_b34_b  = whd + 506880;
    u16* w_b2_b   = whd + 875520;
    u16* w_b4_b   = whd + 1121280;

    zero_kernel<<<8100, 256, 0, stream>>>((uint4*)xpad, 2073600);
    pad_fill<<<7168, 256, 0, stream>>>(base_feat, xpad, im_info);
    wt_transform<<<1024, 256, 0, stream>>>(W_conv, wt, im_info);
    cvt_all<<<4873, 256, 0, stream>>>(W_cls, W_bbox, W_bbox34, W_bbox2, W_bbox4,
                                      b_conv, b_cls, b_bbox, b_bbox34, b_bbox2,
                                      b_bbox4, whd, bfs, im_info);

    conv_gemm256<<<196, 512, 0, stream>>>(xpad, wt, bfs, y);

    pool_all<<<784, 256, 0, stream>>>(y, p4, p8, p12, p16);

    heads_gemm<<<1400, 256, 0, stream>>>(p16, p12, p8, p4,
                                         w_cls_b, w_b1_b, w_b34_b, w_b2_b, w_b4_b,
                                         bfs, clsr, d_out, im_info);

    softmax_all<<<2573, 256, 0, stream>>>(clsr, d_out, im_info);
}